// Round 8
// baseline (399.853 us; speedup 1.0000x reference)
//
#include <hip/hip_runtime.h>
#include <hip/hip_bf16.h>
#include <hip/hip_cooperative_groups.h>

namespace cg = cooperative_groups;

#define EPS 1e-5f
#define NPTS 262144
#define NB 16
#define ACBLK 1024

typedef __attribute__((ext_vector_type(8))) short bf16x8;
typedef __attribute__((ext_vector_type(4))) float f32x4;

// ws float/u32 offsets
#define WS_E    0        // 192 f
#define WS_T    192      // 1024 f
#define WS_W3   1216     // 2048 u32
#define WS_MAXG 3264     // 2048 u32 fallback merged maxima (memset 0 in mode 0)
#define WS_PMOM 5312     // 16*73 f partial moments
#define WS_SCRM 6480     // 1024*73 f per-block moments(9)+hist(64)
#define WS_PART 81232    // 16*2048 u32 partial maxima
#define WS_SMAX 114000   // 1024*2048 u32 per-block maxima

__device__ inline float decodeu(unsigned u){
  unsigned bits = (u & 0x80000000u) ? (u ^ 0x80000000u) : ~u;
  return __uint_as_float(bits);
}
__device__ inline unsigned f2bf(float f){
  unsigned u = __float_as_uint(f);
  return (u + 0x7FFFu + ((u>>16)&1u)) >> 16;
}
__device__ inline unsigned pack2bf(float lo, float hi){
  return (f2bf(hi)<<16) | (f2bf(lo) & 0xFFFFu);
}
__device__ inline unsigned ordu(float v){
  unsigned bits = __float_as_uint(v);
  return bits ^ (unsigned)(((int)bits>>31) | (int)0x80000000);
}

// ================= MEGA KERNEL (cooperative) =================
__global__ __launch_bounds__(256, 4) void kMega(
    const float* __restrict__ feats, const int* __restrict__ bidx,
    const float* __restrict__ W1, const float* __restrict__ g1, const float* __restrict__ b1,
    const float* __restrict__ W2, const float* __restrict__ g2, const float* __restrict__ b2,
    const float* __restrict__ W3, const float* __restrict__ b3,
    float* __restrict__ wsf, float* __restrict__ out) {
  cg::grid_group grid = cg::this_grid();
  __shared__ __align__(16) unsigned char OV[37888];
  int tid = threadIdx.x, blk = blockIdx.x;
  int lane = tid & 63, wv = tid >> 6;

  // ---------- phase A: moments + per-batch directional max ----------
  unsigned* lmaxA = (unsigned*)OV;                 // 2048 u32
  float4* sfeatA  = (float4*)(OV + 8192);          // 256 f4
  float* histA    = (float*)(OV + 12288);          // 64
  float* redA     = (float*)(OV + 12544);          // 36
  for (int i=tid;i<NB*128;i+=256) lmaxA[i]=0u;
  if (tid < NB*4) histA[tid]=0.f;
  __syncthreads();
  int p = blk*256 + tid;
  float f0=feats[3*p], f1=feats[3*p+1], f2=feats[3*p+2];
  int b = bidx[p];
  sfeatA[tid] = make_float4(f0,f1,f2,__int_as_float(b));
  atomicAdd(&histA[b*4+0],f0);
  atomicAdd(&histA[b*4+1],f1);
  atomicAdd(&histA[b*4+2],f2);
  atomicAdd(&histA[b*4+3],1.0f);
  { float acc[9]={f0,f1,f2,f0*f0,f0*f1,f0*f2,f1*f1,f1*f2,f2*f2};
    #pragma unroll
    for (int k=0;k<9;k++){
      float v=acc[k];
      v+=__shfl_down(v,32); v+=__shfl_down(v,16); v+=__shfl_down(v,8);
      v+=__shfl_down(v,4);  v+=__shfl_down(v,2);  v+=__shfl_down(v,1);
      if (lane==0) redA[wv*9+k]=v;
    }
  }
  __syncthreads();
  { int c = (wv&1)*64 + lane;
    float sgn = (g1[c]>=0.f)?1.f:-1.f;
    float w0=W1[3*c]*sgn, w1=W1[3*c+1]*sgn, w2=W1[3*c+2]*sgn;
    const float4* sp = &sfeatA[(wv>>1)*128];
    float m[16];
    #pragma unroll
    for (int q=0;q<16;q++) m[q] = -__builtin_inff();
    #pragma unroll 8
    for (int k=0;k<128;k++){
      float4 f = sp[k];
      float v = fmaf(f.z,w2,fmaf(f.y,w1,f.x*w0));
      int sbb = __builtin_amdgcn_readfirstlane(__float_as_int(f.w));
      switch (sbb){
        case 0:  m[0] = fmaxf(m[0], v); break;
        case 1:  m[1] = fmaxf(m[1], v); break;
        case 2:  m[2] = fmaxf(m[2], v); break;
        case 3:  m[3] = fmaxf(m[3], v); break;
        case 4:  m[4] = fmaxf(m[4], v); break;
        case 5:  m[5] = fmaxf(m[5], v); break;
        case 6:  m[6] = fmaxf(m[6], v); break;
        case 7:  m[7] = fmaxf(m[7], v); break;
        case 8:  m[8] = fmaxf(m[8], v); break;
        case 9:  m[9] = fmaxf(m[9], v); break;
        case 10: m[10] = fmaxf(m[10], v); break;
        case 11: m[11] = fmaxf(m[11], v); break;
        case 12: m[12] = fmaxf(m[12], v); break;
        case 13: m[13] = fmaxf(m[13], v); break;
        case 14: m[14] = fmaxf(m[14], v); break;
        default: m[15] = fmaxf(m[15], v); break;
      }
    }
    #pragma unroll
    for (int q=0;q<16;q++){
      if (m[q] > -__builtin_inff()) atomicMax(&lmaxA[q*128+c], ordu(m[q]));
    }
  }
  __syncthreads();
  { float* scrM = wsf + WS_SCRM + blk*73;
    if (tid<9) scrM[tid]=redA[tid]+redA[9+tid]+redA[18+tid]+redA[27+tid];
    if (tid>=64 && tid<128) scrM[9+tid-64]=histA[tid-64];
    unsigned* spo = (unsigned*)wsf + WS_SMAX + (size_t)blk*2048;
    for (int i=tid;i<2048;i+=256) spo[i]=lmaxA[i];
  }
  grid.sync();

  // ---------- phase M: merge 1024 -> 16 (maxima spread over all blocks) ----------
  { unsigned* lred = (unsigned*)OV;
    if (tid < 32) lred[tid] = 0u;
    __syncthreads();
    int g = blk >> 6;                       // (blk*32)>>11
    int e_base = (blk*32) & 2047;
    int e = e_base + (tid & 31);
    int sub = tid >> 5;
    const unsigned* smax = (const unsigned*)wsf + WS_SMAX;
    unsigned m = 0;
    #pragma unroll
    for (int j=0;j<8;j++){
      unsigned t = smax[(size_t)(g*64 + sub*8 + j)*2048 + e];
      m = t>m?t:m;
    }
    atomicMax(&lred[tid&31], m);
    __syncthreads();
    if (tid < 32) ((unsigned*)wsf)[WS_PART + g*2048 + e_base + tid] = lred[tid];
    // moments merge: blocks 16..307, one task per wave
    if (blk >= 16 && blk < 308){
      int task = (blk-16)*4 + wv;
      if (task < 16*73){
        int g2i = task/73, mm = task - g2i*73;
        float v = wsf[WS_SCRM + (size_t)(g2i*64+lane)*73 + mm];
        v+=__shfl_down(v,32); v+=__shfl_down(v,16); v+=__shfl_down(v,8);
        v+=__shfl_down(v,4);  v+=__shfl_down(v,2);  v+=__shfl_down(v,1);
        if (lane==0) wsf[WS_PMOM + g2i*73 + mm] = v;
      }
    }
  }
  grid.sync();

  // ---------- phase B: tiny math on block 0 ----------
  if (blk == 0) {
    float* smbnf = (float*)OV;                    // 2048 f
    float4* smbnq = (float4*)OV;
    float* srhs  = (float*)(OV + 8192);           // 512 f
    float4* srhsq = (float4*)(OV + 8192);
    float* s_w1  = (float*)(OV + 10240);          // 384
    float* s_sc  = (float*)(OV + 11776);          // 128
    float* s_sh  = (float*)(OV + 12288);          // 128
    float* smom  = (float*)(OV + 12800);          // 80
    float* sTb   = (float*)(OV + 13120);          // 1024
    float* sE    = (float*)(OV + 17216);          // 192
    float* sgv   = (float*)(OV + 17984);          // 64
    float* s_s2  = (float*)(OV + 18240);          // 64
    float* s_t2  = (float*)(OV + 18496);          // 64
    // early global loads: W2 rows into regs (owner: c=lane, q=wv)
    float4 rw[16];
    #pragma unroll
    for (int t=0;t<16;t++) rw[t] = ((const float4*)W2)[lane*64 + wv*16 + t];
    float4 rw3[4];
    #pragma unroll
    for (int t=0;t<4;t++) rw3[t] = ((const float4*)W3)[tid + t*256];
    for (int i=tid;i<384;i+=256) s_w1[i]=W1[i];
    if (tid<73){ float s=0;
      #pragma unroll
      for (int g=0;g<16;g++) s += wsf[WS_PMOM+g*73+tid];
      smom[tid]=s; }
    for (int i=tid;i<1024;i+=256) sTb[i]=0.f;
    if (tid<192) sE[tid]=0.f;
    if (tid<64) sgv[tid]=0.f;
    __syncthreads();
    const float invN = 1.0f/NPTS;
    if (tid < 128){
      int c=tid; float w0=s_w1[3*c],w1=s_w1[3*c+1],w2=s_w1[3*c+2];
      float mean = (w0*smom[0]+w1*smom[1]+w2*smom[2])*invN;
      float ex2 = (w0*w0*smom[3]+w1*w1*smom[6]+w2*w2*smom[8]
                 + 2.f*(w0*w1*smom[4]+w0*w2*smom[5]+w1*w2*smom[7]))*invN;
      float var = ex2 - mean*mean;
      float sc = g1[c]*rsqrtf(var+EPS);
      s_sc[c]=sc; s_sh[c]=b1[c]-mean*sc;
    }
    __syncthreads();
    { const unsigned* part=(const unsigned*)wsf+WS_PART;
      for (int i=tid;i<2048;i+=256){
        unsigned u=0;
        #pragma unroll
        for (int g=0;g<16;g++){ unsigned t=part[g*2048+i]; u = t>u?t:u; }
        float M = decodeu(u);
        int ch=i&127;
        smbnf[i] = fabsf(s_sc[ch])*M + s_sh[ch];
      } }
    for (int i=tid;i<512;i+=256){
      int which=i>>7, j=i&127;
      srhs[i] = (which<3)? s_sc[j]*s_w1[3*j+which] : s_sh[j];
    }
    __syncthreads();
    // dots: wave-uniform quarter q=wv; c=lane
    if (wv >= 2){
      float pt[16];
      #pragma unroll
      for (int bq=0;bq<16;bq++){
        float s=0;
        #pragma unroll
        for (int i=0;i<16;i++){
          float4 a = rw[i];
          float4 r = smbnq[bq*32 + (wv-2)*16 + i];
          s = fmaf(a.x,r.x,fmaf(a.y,r.y,fmaf(a.z,r.z,fmaf(a.w,r.w,s))));
        }
        pt[bq]=s;
      }
      #pragma unroll
      for (int bq=0;bq<16;bq++) atomicAdd(&sTb[bq*64+lane], pt[bq]);
    } else {
      float pe[4];
      #pragma unroll
      for (int r=0;r<4;r++){
        float s=0;
        #pragma unroll
        for (int i=0;i<16;i++){
          float4 a = rw[i];
          float4 rv = srhsq[r*32 + wv*16 + i];
          s = fmaf(a.x,rv.x,fmaf(a.y,rv.y,fmaf(a.z,rv.z,fmaf(a.w,rv.w,s))));
        }
        pe[r]=s;
      }
      #pragma unroll
      for (int r=0;r<4;r++){
        if (r<3) atomicAdd(&sE[r*64+lane], pe[r]);
        else     atomicAdd(&sgv[lane], pe[r]);
      }
    }
    __syncthreads();
    if (tid < 64){
      int c=tid;
      float e0=sE[c],e1=sE[64+c],e2=sE[128+c],gc=sgv[c];
      float sumY = e0*smom[0]+e1*smom[1]+e2*smom[2];
      float sumYY = e0*e0*smom[3]+e1*e1*smom[6]+e2*e2*smom[8]
                 + 2.f*(e0*e1*smom[4]+e0*e2*smom[5]+e1*e2*smom[7]);
      #pragma unroll
      for (int bq=0;bq<NB;bq++){
        float nb = smom[9+bq*4+3];
        float hb = gc + sTb[bq*64+c];
        float eS1b = e0*smom[9+bq*4]+e1*smom[9+bq*4+1]+e2*smom[9+bq*4+2];
        sumY += nb*hb;
        sumYY += 2.f*hb*eS1b + nb*hb*hb;
      }
      float mean2 = sumY*invN;
      float var2 = sumYY*invN - mean2*mean2;
      float s2 = g2[c]*rsqrtf(var2+EPS);
      float t2 = b2[c]-mean2*s2;
      s_s2[c]=s2; s_t2[c]=t2;
      wsf[WS_E + c] = e0*s2; wsf[WS_E+64+c]=e1*s2; wsf[WS_E+128+c]=e2*s2;
    }
    __syncthreads();
    for (int i=tid;i<1024;i+=256){
      int cc=i&63;
      wsf[WS_T + i] = (sgv[cc]+sTb[i])*s_s2[cc] + s_t2[cc];
    }
    { unsigned* w3u = (unsigned*)wsf + WS_W3;
      #pragma unroll
      for (int t=0;t<4;t++){
        int q = tid + t*256;
        w3u[2*q]   = pack2bf(rw3[t].x, rw3[t].y);
        w3u[2*q+1] = pack2bf(rw3[t].z, rw3[t].w);
      } }
  }
  grid.sync();

  // ---------- phase F: y2 -> bn2/relu -> z@W3.T + b3 (points still in regs) ----------
  { unsigned* zbuf = (unsigned*)OV;               // 32KB
    float* Tl = (float*)(OV + 32768);             // 16*66
    float* sEg = (float*)(OV + 36992);            // 192
    for (int i=tid;i<NB*64;i+=256) Tl[(i>>6)*66 + (i&63)] = wsf[WS_T + i];
    if (tid<192) sEg[tid] = wsf[WS_E + tid];
    int col = lane & 15, kgrp = lane >> 4;
    const ushort* w3b = (const ushort*)((const unsigned*)wsf + WS_W3);
    bf16x8 bfr[4][2];
    #pragma unroll
    for (int n=0;n<4;n++)
      #pragma unroll
      for (int kk=0;kk<2;kk++)
        bfr[n][kk] = *(const bf16x8*)(w3b + (n*16+col)*64 + kk*32 + kgrp*8);
    float bias[4];
    #pragma unroll
    for (int n=0;n<4;n++) bias[n] = b3[n*16+col];
    __syncthreads();
    const float* tb = &Tl[b*66];
    unsigned rowbase = (unsigned)tid*32;
    unsigned sw = (lane&7)<<2;
    #pragma unroll
    for (int j=0;j<8;j++){
      unsigned w[4];
      #pragma unroll
      for (int q=0;q<4;q++){
        int c = j*8 + q*2;
        float2 e0p = *(const float2*)(sEg + c);
        float2 e1p = *(const float2*)(sEg + 64 + c);
        float2 e2p = *(const float2*)(sEg + 128 + c);
        float2 tp  = *(const float2*)(tb + c);
        float y0 = fmaf(e0p.x,f0, fmaf(e1p.x,f1, fmaf(e2p.x,f2, tp.x)));
        float y1 = fmaf(e0p.y,f0, fmaf(e1p.y,f1, fmaf(e2p.y,f2, tp.y)));
        w[q] = pack2bf(fmaxf(y0,0.f), fmaxf(y1,0.f));
      }
      uint4 ch; ch.x=w[0]; ch.y=w[1]; ch.z=w[2]; ch.w=w[3];
      *(uint4*)&zbuf[rowbase + (((unsigned)(j*4)) ^ sw)] = ch;
    }
    __syncthreads();
    int p0w = blk*256 + wv*64;
    #pragma unroll
    for (int mh=0;mh<2;mh++){
      bf16x8 af[2][2];
      #pragma unroll
      for (int mi=0;mi<2;mi++){
        int m = mh*2+mi;
        int row = m*16 + col;
        unsigned rb = (unsigned)(wv*64+row)*32;
        unsigned sw2 = (unsigned)(row&7)<<2;
        af[mi][0] = *(const bf16x8*)&zbuf[rb + (((unsigned)(kgrp*4)) ^ sw2)];
        af[mi][1] = *(const bf16x8*)&zbuf[rb + (((unsigned)(16 + kgrp*4)) ^ sw2)];
      }
      f32x4 acc[2][4];
      #pragma unroll
      for (int mi=0;mi<2;mi++)
        #pragma unroll
        for (int n=0;n<4;n++)
          acc[mi][n] = (f32x4){0.f,0.f,0.f,0.f};
      #pragma unroll
      for (int kk=0;kk<2;kk++)
        #pragma unroll
        for (int mi=0;mi<2;mi++)
          #pragma unroll
          for (int n=0;n<4;n++)
            acc[mi][n] = __builtin_amdgcn_mfma_f32_16x16x32_bf16(af[mi][kk], bfr[n][kk], acc[mi][n], 0,0,0);
      #pragma unroll
      for (int mi=0;mi<2;mi++){
        int prow = p0w + (mh*2+mi)*16 + kgrp*4;
        #pragma unroll
        for (int n=0;n<4;n++){
          int cg = n*16+col;
          #pragma unroll
          for (int r=0;r<4;r++)
            out[(size_t)(prow+r)*64 + cg] = acc[mi][n][r] + bias[n];
        }
      }
    }
  }
}

// ================= LEGACY 4-KERNEL PATH (fallback) =================
__global__ __launch_bounds__(256) void kAC(const float* __restrict__ feats,
                                           const int* __restrict__ bidx,
                                           const float* __restrict__ W1,
                                           const float* __restrict__ g1,
                                           float* __restrict__ wsf, int mode) {
  __shared__ unsigned lmax[NB*128];
  __shared__ __align__(16) float4 sfeat[256];
  __shared__ float hist[NB*4];
  __shared__ float red[4*9];
  int tid = threadIdx.x;
  for (int i=tid;i<NB*128;i+=256) lmax[i]=0u;
  if (tid < NB*4) hist[tid]=0.f;
  __syncthreads();
  int p = blockIdx.x*256 + tid;
  float f0=feats[3*p], f1=feats[3*p+1], f2=feats[3*p+2];
  int b = bidx[p];
  sfeat[tid] = make_float4(f0,f1,f2,__int_as_float(b));
  atomicAdd(&hist[b*4+0],f0);
  atomicAdd(&hist[b*4+1],f1);
  atomicAdd(&hist[b*4+2],f2);
  atomicAdd(&hist[b*4+3],1.0f);
  int lane = tid&63, wv = tid>>6;
  { float acc[9]={f0,f1,f2,f0*f0,f0*f1,f0*f2,f1*f1,f1*f2,f2*f2};
    #pragma unroll
    for (int k=0;k<9;k++){
      float v=acc[k];
      v+=__shfl_down(v,32); v+=__shfl_down(v,16); v+=__shfl_down(v,8);
      v+=__shfl_down(v,4);  v+=__shfl_down(v,2);  v+=__shfl_down(v,1);
      if (lane==0) red[wv*9+k]=v;
    }
  }
  __syncthreads();
  int c = (wv&1)*64 + lane;
  float sgn = (g1[c]>=0.f)?1.f:-1.f;
  float w0=W1[3*c]*sgn, w1=W1[3*c+1]*sgn, w2=W1[3*c+2]*sgn;
  const float4* sp = &sfeat[(wv>>1)*128];
  float m[16];
  #pragma unroll
  for (int q=0;q<16;q++) m[q] = -__builtin_inff();
  #pragma unroll 8
  for (int k=0;k<128;k++){
    float4 f = sp[k];
    float v = fmaf(f.z,w2,fmaf(f.y,w1,f.x*w0));
    int sbb = __builtin_amdgcn_readfirstlane(__float_as_int(f.w));
    switch (sbb){
      case 0:  m[0] = fmaxf(m[0], v); break;
      case 1:  m[1] = fmaxf(m[1], v); break;
      case 2:  m[2] = fmaxf(m[2], v); break;
      case 3:  m[3] = fmaxf(m[3], v); break;
      case 4:  m[4] = fmaxf(m[4], v); break;
      case 5:  m[5] = fmaxf(m[5], v); break;
      case 6:  m[6] = fmaxf(m[6], v); break;
      case 7:  m[7] = fmaxf(m[7], v); break;
      case 8:  m[8] = fmaxf(m[8], v); break;
      case 9:  m[9] = fmaxf(m[9], v); break;
      case 10: m[10] = fmaxf(m[10], v); break;
      case 11: m[11] = fmaxf(m[11], v); break;
      case 12: m[12] = fmaxf(m[12], v); break;
      case 13: m[13] = fmaxf(m[13], v); break;
      case 14: m[14] = fmaxf(m[14], v); break;
      default: m[15] = fmaxf(m[15], v); break;
    }
  }
  #pragma unroll
  for (int q=0;q<16;q++){
    if (m[q] > -__builtin_inff()) atomicMax(&lmax[q*128+c], ordu(m[q]));
  }
  __syncthreads();
  float* scrM = wsf + WS_SCRM + blockIdx.x*73;
  if (tid<9) scrM[tid]=red[tid]+red[9+tid]+red[18+tid]+red[27+tid];
  if (tid>=64 && tid<128) scrM[9+tid-64]=hist[tid-64];
  if (mode){
    unsigned* spo = (unsigned*)wsf + WS_SMAX + (size_t)blockIdx.x*2048;
    for (int i=tid;i<2048;i+=256) spo[i]=lmax[i];
  } else {
    unsigned* mg = (unsigned*)wsf + WS_MAXG;
    for (int i=tid;i<2048;i+=256){ unsigned v=lmax[i]; if(v) atomicMax(&mg[i],v); }
  }
}

__global__ __launch_bounds__(256) void kM(float* __restrict__ wsf){
  int g = blockIdx.x >> 3, ec = blockIdx.x & 7;
  int e = ec*256 + threadIdx.x;
  const unsigned* smax = (const unsigned*)wsf + WS_SMAX;
  unsigned m = 0;
  #pragma unroll 4
  for (int k=g*64;k<g*64+64;k++){ unsigned t=smax[(size_t)k*2048+e]; m = t>m?t:m; }
  ((unsigned*)wsf)[WS_PART + g*2048 + e] = m;
  if (ec==0 && threadIdx.x<73){
    float s=0; const float* sm0 = wsf + WS_SCRM;
    #pragma unroll 4
    for (int k=g*64;k<g*64+64;k++) s += sm0[k*73+threadIdx.x];
    wsf[WS_PMOM + g*73 + threadIdx.x] = s;
  }
}

__global__ __launch_bounds__(1024) void kB(float* __restrict__ wsf,
    const float* __restrict__ W1, const float* __restrict__ g1, const float* __restrict__ b1,
    const float* __restrict__ W2, const float* __restrict__ g2, const float* __restrict__ b2,
    const float* __restrict__ W3, int mode) {
  __shared__ __align__(16) float4 w2q[64*66];
  __shared__ __align__(16) float4 smbnq[NB*32];
  __shared__ __align__(16) float4 srhsq[4*32];
  __shared__ float s_w1[384];
  __shared__ float s_sc[128], s_sh[128], sE[3*64], sg[64], sT[NB*64];
  __shared__ float smom[80], s_s2[64], s_t2[64];
  int tid = threadIdx.x;
  float4 rw[4];
  #pragma unroll
  for (int t=0;t<4;t++) rw[t] = ((const float4*)W2)[tid + t*1024];
  float4 rw3 = ((const float4*)W3)[tid];
  if (tid<384) s_w1[tid]=W1[tid];
  #pragma unroll
  for (int t=0;t<4;t++){
    int q = tid + t*1024;
    w2q[(q&63)*66 + (q>>6)] = rw[t];
  }
  { unsigned* w3u = (unsigned*)wsf + WS_W3;
    w3u[2*tid]   = pack2bf(rw3.x, rw3.y);
    w3u[2*tid+1] = pack2bf(rw3.z, rw3.w);
  }
  if (mode){
    if (tid<73){ float s=0;
      #pragma unroll
      for (int g=0;g<16;g++) s += wsf[WS_PMOM+g*73+tid];
      smom[tid]=s; }
  } else {
    if (tid<73){ float s=0; const float* sm0=wsf+WS_SCRM;
      for (int k=0;k<ACBLK;k++) s += sm0[k*73+tid];
      smom[tid]=s; }
  }
  __syncthreads();
  const float invN = 1.0f/NPTS;
  if (tid < 128){
    int c=tid; float w0=s_w1[3*c],w1=s_w1[3*c+1],w2=s_w1[3*c+2];
    float mean = (w0*smom[0]+w1*smom[1]+w2*smom[2])*invN;
    float ex2 = (w0*w0*smom[3]+w1*w1*smom[6]+w2*w2*smom[8]
               + 2.f*(w0*w1*smom[4]+w0*w2*smom[5]+w1*w2*smom[7]))*invN;
    float var = ex2 - mean*mean;
    float sc = g1[c]*rsqrtf(var+EPS);
    s_sc[c]=sc; s_sh[c]=b1[c]-mean*sc;
  }
  __syncthreads();
  { const unsigned* part=(const unsigned*)wsf+WS_PART;
    const unsigned* mg=(const unsigned*)wsf+WS_MAXG;
    float* smbnf = (float*)smbnq;
    #pragma unroll
    for (int i=tid;i<NB*128;i+=1024){
      unsigned u;
      if (mode){ u=0;
        #pragma unroll
        for (int g=0;g<16;g++){ unsigned t=part[g*2048+i]; u = t>u?t:u; }
      } else u = mg[i];
      float M = decodeu(u);
      int ch=i&127;
      smbnf[i] = fabsf(s_sc[ch])*M + s_sh[ch];
    } }
  if (tid < 512){
    int which = tid>>7, j = tid&127;
    ((float*)srhsq)[tid] = (which<3) ? s_sc[j]*s_w1[3*j+which] : s_sh[j];
  }
  __syncthreads();
  { int c = tid&63, b = tid>>6;
    const float4* rq = &smbnq[b*32];
    float s=0;
    #pragma unroll 8
    for (int jj=0;jj<32;jj++){
      float4 a = w2q[(32+jj)*66 + c];
      float4 r = rq[jj];
      s = fmaf(a.x,r.x,fmaf(a.y,r.y,fmaf(a.z,r.z,fmaf(a.w,r.w,s))));
    }
    sT[b*64+c] = s;
    if (tid < 256){
      int which = tid>>6;
      float s2=0;
      #pragma unroll 8
      for (int jj=0;jj<32;jj++){
        float4 a = w2q[jj*66 + c];
        float4 r = srhsq[which*32+jj];
        s2 = fmaf(a.x,r.x,fmaf(a.y,r.y,fmaf(a.z,r.z,fmaf(a.w,r.w,s2))));
      }
      if (which<3) sE[which*64+c]=s2; else sg[c]=s2;
    }
  }
  __syncthreads();
  if (tid < 64){
    int c=tid;
    float e0=sE[c],e1=sE[64+c],e2=sE[128+c],gc=sg[c];
    float sumY = e0*smom[0]+e1*smom[1]+e2*smom[2];
    float sumYY = e0*e0*smom[3]+e1*e1*smom[6]+e2*e2*smom[8]
               + 2.f*(e0*e1*smom[4]+e0*e2*smom[5]+e1*e2*smom[7]);
    #pragma unroll
    for (int b=0;b<NB;b++){
      float nb = smom[9+b*4+3];
      float hb = gc + sT[b*64+c];
      float eS1b = e0*smom[9+b*4]+e1*smom[9+b*4+1]+e2*smom[9+b*4+2];
      sumY += nb*hb;
      sumYY += 2.f*hb*eS1b + nb*hb*hb;
    }
    float mean2 = sumY*invN;
    float var2 = sumYY*invN - mean2*mean2;
    float s2 = g2[c]*rsqrtf(var2+EPS);
    float t2 = b2[c]-mean2*s2;
    s_s2[c]=s2; s_t2[c]=t2;
    wsf[WS_E + c] = e0*s2; wsf[WS_E+64+c]=e1*s2; wsf[WS_E+128+c]=e2*s2;
  }
  __syncthreads();
  { int c=tid&63;
    if (tid < NB*64) wsf[WS_T + tid] = (sg[c]+sT[tid])*s_s2[c] + s_t2[c];
  }
}

__global__ __launch_bounds__(256) void kF(const float* __restrict__ feats,
                                          const int* __restrict__ bidx,
                                          const float* __restrict__ wsf,
                                          const float* __restrict__ b3,
                                          float* __restrict__ out) {
  __shared__ __align__(16) float Tl[NB*66];
  __shared__ __align__(16) unsigned zbuf[4*64*32];
  int tid = threadIdx.x;
  for (int i=tid;i<NB*64;i+=256) Tl[(i>>6)*66 + (i&63)] = wsf[WS_T + i];
  int lane = tid & 63, wv = tid >> 6;
  int col = lane & 15, kgrp = lane >> 4;
  const ushort* w3b = (const ushort*)((const unsigned*)wsf + WS_W3);
  bf16x8 bfr[4][2];
  #pragma unroll
  for (int n=0;n<4;n++)
    #pragma unroll
    for (int kk=0;kk<2;kk++)
      bfr[n][kk] = *(const bf16x8*)(w3b + (n*16+col)*64 + kk*32 + kgrp*8);
  float bias[4];
  #pragma unroll
  for (int n=0;n<4;n++) bias[n] = b3[n*16+col];
  __syncthreads();
  const float* Eg = wsf + WS_E;
  int p0 = (blockIdx.x*4 + wv)*64;
  int p = p0 + lane;
  float f0 = feats[3*p], f1 = feats[3*p+1], f2 = feats[3*p+2];
  int b = bidx[p];
  const float* tb = &Tl[b*66];
  unsigned rowbase = (unsigned)(wv*64+lane)*32;
  unsigned sw = (lane&7)<<2;
  #pragma unroll
  for (int j=0;j<8;j++){
    unsigned w[4];
    #pragma unroll
    for (int q=0;q<4;q++){
      int c = j*8 + q*2;
      float2 tp = *(const float2*)(tb + c);
      float y0 = fmaf(Eg[c],  f0, fmaf(Eg[64+c],  f1, fmaf(Eg[128+c],  f2, tp.x)));
      float y1 = fmaf(Eg[c+1],f0, fmaf(Eg[64+c+1],f1, fmaf(Eg[128+c+1],f2, tp.y)));
      w[q] = pack2bf(fmaxf(y0,0.f), fmaxf(y1,0.f));
    }
    uint4 ch; ch.x=w[0]; ch.y=w[1]; ch.z=w[2]; ch.w=w[3];
    *(uint4*)&zbuf[rowbase + (((unsigned)(j*4)) ^ sw)] = ch;
  }
  __syncthreads();
  bf16x8 af[4][2];
  #pragma unroll
  for (int m=0;m<4;m++){
    int row = m*16 + col;
    unsigned rb = (unsigned)(wv*64+row)*32;
    unsigned sw2 = (unsigned)(row&7)<<2;
    #pragma unroll
    for (int kk=0;kk<2;kk++){
      unsigned off = ((unsigned)(kk*16 + kgrp*4)) ^ sw2;
      af[m][kk] = *(const bf16x8*)&zbuf[rb + off];
    }
  }
  f32x4 acc[4][4];
  #pragma unroll
  for (int m=0;m<4;m++)
    #pragma unroll
    for (int n=0;n<4;n++)
      acc[m][n] = (f32x4){0.f,0.f,0.f,0.f};
  #pragma unroll
  for (int kk=0;kk<2;kk++)
    #pragma unroll
    for (int m=0;m<4;m++)
      #pragma unroll
      for (int n=0;n<4;n++)
        acc[m][n] = __builtin_amdgcn_mfma_f32_16x16x32_bf16(af[m][kk], bfr[n][kk], acc[m][n], 0,0,0);
  #pragma unroll
  for (int m=0;m<4;m++){
    int prow = p0 + m*16 + kgrp*4;
    #pragma unroll
    for (int n=0;n<4;n++){
      int cg = n*16+col;
      #pragma unroll
      for (int r=0;r<4;r++)
        out[(size_t)(prow+r)*64 + cg] = acc[m][n][r] + bias[n];
    }
  }
}

extern "C" void kernel_launch(void* const* d_in, const int* in_sizes, int n_in,
                              void* d_out, int out_size, void* d_ws, size_t ws_size,
                              hipStream_t stream) {
  const float* feats = (const float*)d_in[0];
  const int*   bidx  = (const int*)d_in[1];
  const float* W1 = (const float*)d_in[2];
  const float* g1 = (const float*)d_in[3];
  const float* b1 = (const float*)d_in[4];
  const float* W2 = (const float*)d_in[5];
  const float* g2 = (const float*)d_in[6];
  const float* b2 = (const float*)d_in[7];
  const float* W3 = (const float*)d_in[8];
  const float* b3 = (const float*)d_in[9];
  float* wsf = (float*)d_ws;
  float* out = (float*)d_out;
  size_t need = (size_t)(WS_SMAX + (size_t)ACBLK*2048)*4;
  int mode = (ws_size >= need) ? 1 : 0;
  if (mode) {
    void* args[] = {(void*)&feats, (void*)&bidx, (void*)&W1, (void*)&g1, (void*)&b1,
                    (void*)&W2, (void*)&g2, (void*)&b2, (void*)&W3, (void*)&b3,
                    (void*)&wsf, (void*)&out};
    hipError_t err = hipLaunchCooperativeKernel((const void*)kMega, dim3(ACBLK), dim3(256),
                                                args, 0, stream);
    if (err == hipSuccess) return;
    (void)hipGetLastError();  // clear sticky error, fall through to legacy path
  }
  if (!mode) (void)hipMemsetAsync((char*)d_ws + (size_t)WS_MAXG*4, 0, 2048*4, stream);
  kAC<<<ACBLK, 256, 0, stream>>>(feats, bidx, W1, g1, wsf, mode);
  if (mode) kM<<<128, 256, 0, stream>>>(wsf);
  kB<<<1, 1024, 0, stream>>>(wsf, W1,g1,b1, W2,g2,b2, W3, mode);
  kF<<<1024, 256, 0, stream>>>(feats, bidx, wsf, b3, out);
}

// Round 9
// 60.483 us; speedup vs baseline: 6.6110x; 6.6110x over previous
//
#include <hip/hip_runtime.h>
#include <hip/hip_bf16.h>

#define EPS 1e-5f
#define NPTS 262144
#define NB 16
#define ACBLK 1024

typedef __attribute__((ext_vector_type(8))) short bf16x8;
typedef __attribute__((ext_vector_type(4))) float f32x4;

// ws float/u32 offsets
#define WS_E    0        // 192 f
#define WS_T    192      // 1024 f
#define WS_W3   1216     // 2048 u32
#define WS_MAXG 3264     // 2048 u32 fallback merged maxima (memset 0 in mode 0)
#define WS_PMOM 5312     // 16*73 f kM partial moments
#define WS_SCRM 6480     // 1024*73 f per-block moments(9)+hist(64)
#define WS_PART 81232    // 16*2048 u32 kM partial maxima
#define WS_SMAX 114000   // 1024*2048 u32 per-block maxima

__device__ inline float decodeu(unsigned u){
  unsigned bits = (u & 0x80000000u) ? (u ^ 0x80000000u) : ~u;
  return __uint_as_float(bits);
}
__device__ inline unsigned f2bf(float f){
  unsigned u = __float_as_uint(f);
  return (u + 0x7FFFu + ((u>>16)&1u)) >> 16;
}
__device__ inline unsigned pack2bf(float lo, float hi){
  return (f2bf(hi)<<16) | (f2bf(lo) & 0xFFFFu);
}
__device__ inline unsigned ordu(float v){
  unsigned bits = __float_as_uint(v);
  return bits ^ (unsigned)(((int)bits>>31) | (int)0x80000000);
}

// ---- kAC: fused moments + per-batch directional max of feats@W1'^T ----
__global__ __launch_bounds__(256) void kAC(const float* __restrict__ feats,
                                           const int* __restrict__ bidx,
                                           const float* __restrict__ W1,
                                           const float* __restrict__ g1,
                                           float* __restrict__ wsf, int mode) {
  __shared__ unsigned lmax[NB*128];
  __shared__ __align__(16) float4 sfeat[256];
  __shared__ float hist[NB*4];
  __shared__ float red[4*9];
  int tid = threadIdx.x;
  for (int i=tid;i<NB*128;i+=256) lmax[i]=0u;
  if (tid < NB*4) hist[tid]=0.f;
  __syncthreads();
  int p = blockIdx.x*256 + tid;
  float f0=feats[3*p], f1=feats[3*p+1], f2=feats[3*p+2];
  int b = bidx[p];
  sfeat[tid] = make_float4(f0,f1,f2,__int_as_float(b));
  atomicAdd(&hist[b*4+0],f0);
  atomicAdd(&hist[b*4+1],f1);
  atomicAdd(&hist[b*4+2],f2);
  atomicAdd(&hist[b*4+3],1.0f);
  int lane = tid&63, wv = tid>>6;
  { float acc[9]={f0,f1,f2,f0*f0,f0*f1,f0*f2,f1*f1,f1*f2,f2*f2};
    #pragma unroll
    for (int k=0;k<9;k++){
      float v=acc[k];
      v+=__shfl_down(v,32); v+=__shfl_down(v,16); v+=__shfl_down(v,8);
      v+=__shfl_down(v,4);  v+=__shfl_down(v,2);  v+=__shfl_down(v,1);
      if (lane==0) red[wv*9+k]=v;
    }
  }
  __syncthreads();
  int c = (wv&1)*64 + lane;
  float sgn = (g1[c]>=0.f)?1.f:-1.f;
  float w0=W1[3*c]*sgn, w1=W1[3*c+1]*sgn, w2=W1[3*c+2]*sgn;
  const float4* sp = &sfeat[(wv>>1)*128];
  float m[16];
  #pragma unroll
  for (int q=0;q<16;q++) m[q] = -__builtin_inff();
  #pragma unroll 8
  for (int k=0;k<128;k++){
    float4 f = sp[k];
    float v = fmaf(f.z,w2,fmaf(f.y,w1,f.x*w0));
    int sbb = __builtin_amdgcn_readfirstlane(__float_as_int(f.w));
    switch (sbb){
      case 0:  m[0] = fmaxf(m[0], v); break;
      case 1:  m[1] = fmaxf(m[1], v); break;
      case 2:  m[2] = fmaxf(m[2], v); break;
      case 3:  m[3] = fmaxf(m[3], v); break;
      case 4:  m[4] = fmaxf(m[4], v); break;
      case 5:  m[5] = fmaxf(m[5], v); break;
      case 6:  m[6] = fmaxf(m[6], v); break;
      case 7:  m[7] = fmaxf(m[7], v); break;
      case 8:  m[8] = fmaxf(m[8], v); break;
      case 9:  m[9] = fmaxf(m[9], v); break;
      case 10: m[10] = fmaxf(m[10], v); break;
      case 11: m[11] = fmaxf(m[11], v); break;
      case 12: m[12] = fmaxf(m[12], v); break;
      case 13: m[13] = fmaxf(m[13], v); break;
      case 14: m[14] = fmaxf(m[14], v); break;
      default: m[15] = fmaxf(m[15], v); break;
    }
  }
  #pragma unroll
  for (int q=0;q<16;q++){
    if (m[q] > -__builtin_inff()) atomicMax(&lmax[q*128+c], ordu(m[q]));
  }
  __syncthreads();
  float* scrM = wsf + WS_SCRM + blockIdx.x*73;
  if (tid<9) scrM[tid]=red[tid]+red[9+tid]+red[18+tid]+red[27+tid];
  if (tid>=64 && tid<128) scrM[9+tid-64]=hist[tid-64];
  if (mode){
    unsigned* spo = (unsigned*)wsf + WS_SMAX + (size_t)blockIdx.x*2048;
    for (int i=tid;i<2048;i+=256) spo[i]=lmax[i];
  } else {
    unsigned* mg = (unsigned*)wsf + WS_MAXG;
    for (int i=tid;i<2048;i+=256){ unsigned v=lmax[i]; if(v) atomicMax(&mg[i],v); }
  }
}

// ---- kM: tree-merge per-block maxima 1024->16, moments 1024->16 ----
__global__ __launch_bounds__(256) void kM(float* __restrict__ wsf){
  int g = blockIdx.x >> 3, ec = blockIdx.x & 7;
  int e = ec*256 + threadIdx.x;
  const unsigned* smax = (const unsigned*)wsf + WS_SMAX;
  unsigned m = 0;
  #pragma unroll 4
  for (int k=g*64;k<g*64+64;k++){ unsigned t=smax[(size_t)k*2048+e]; m = t>m?t:m; }
  ((unsigned*)wsf)[WS_PART + g*2048 + e] = m;
  if (ec==0 && threadIdx.x<73){
    float s=0; const float* sm0 = wsf + WS_SCRM;
    #pragma unroll 4
    for (int k=g*64;k<g*64+64;k++) s += sm0[k*73+threadIdx.x];
    wsf[WS_PMOM + g*73 + threadIdx.x] = s;
  }
}

// ---- kB: all tiny math (single block, 1024 thr, float4 LDS dots) ----
__global__ __launch_bounds__(1024) void kB(float* __restrict__ wsf,
    const float* __restrict__ W1, const float* __restrict__ g1, const float* __restrict__ b1,
    const float* __restrict__ W2, const float* __restrict__ g2, const float* __restrict__ b2,
    const float* __restrict__ W3, int mode) {
  __shared__ __align__(16) float4 w2q[64*66];
  __shared__ __align__(16) float4 smbnq[NB*32];
  __shared__ __align__(16) float4 srhsq[4*32];
  __shared__ float s_w1[384];
  __shared__ float s_sc[128], s_sh[128], sE[3*64], sg[64], sT[NB*64];
  __shared__ float smom[80], s_s2[64], s_t2[64];
  int tid = threadIdx.x;
  float4 rw[4];
  #pragma unroll
  for (int t=0;t<4;t++) rw[t] = ((const float4*)W2)[tid + t*1024];
  float4 rw3 = ((const float4*)W3)[tid];
  if (tid<384) s_w1[tid]=W1[tid];
  #pragma unroll
  for (int t=0;t<4;t++){
    int q = tid + t*1024;
    w2q[(q&63)*66 + (q>>6)] = rw[t];
  }
  { unsigned* w3u = (unsigned*)wsf + WS_W3;
    w3u[2*tid]   = pack2bf(rw3.x, rw3.y);
    w3u[2*tid+1] = pack2bf(rw3.z, rw3.w);
  }
  if (mode){
    if (tid<73){ float s=0;
      #pragma unroll
      for (int g=0;g<16;g++) s += wsf[WS_PMOM+g*73+tid];
      smom[tid]=s; }
  } else {
    if (tid<73){ float s=0; const float* sm0=wsf+WS_SCRM;
      for (int k=0;k<ACBLK;k++) s += sm0[k*73+tid];
      smom[tid]=s; }
  }
  __syncthreads();
  const float invN = 1.0f/NPTS;
  if (tid < 128){
    int c=tid; float w0=s_w1[3*c],w1=s_w1[3*c+1],w2=s_w1[3*c+2];
    float mean = (w0*smom[0]+w1*smom[1]+w2*smom[2])*invN;
    float ex2 = (w0*w0*smom[3]+w1*w1*smom[6]+w2*w2*smom[8]
               + 2.f*(w0*w1*smom[4]+w0*w2*smom[5]+w1*w2*smom[7]))*invN;
    float var = ex2 - mean*mean;
    float sc = g1[c]*rsqrtf(var+EPS);
    s_sc[c]=sc; s_sh[c]=b1[c]-mean*sc;
  }
  __syncthreads();
  { const unsigned* part=(const unsigned*)wsf+WS_PART;
    const unsigned* mg=(const unsigned*)wsf+WS_MAXG;
    float* smbnf = (float*)smbnq;
    #pragma unroll
    for (int i=tid;i<NB*128;i+=1024){
      unsigned u;
      if (mode){ u=0;
        #pragma unroll
        for (int g=0;g<16;g++){ unsigned t=part[g*2048+i]; u = t>u?t:u; }
      } else u = mg[i];
      float M = decodeu(u);
      int ch=i&127;
      smbnf[i] = fabsf(s_sc[ch])*M + s_sh[ch];
    } }
  if (tid < 512){
    int which = tid>>7, j = tid&127;
    ((float*)srhsq)[tid] = (which<3) ? s_sc[j]*s_w1[3*j+which] : s_sh[j];
  }
  __syncthreads();
  { int c = tid&63, b = tid>>6;
    const float4* rq = &smbnq[b*32];
    float s=0;
    #pragma unroll 8
    for (int jj=0;jj<32;jj++){
      float4 a = w2q[(32+jj)*66 + c];
      float4 r = rq[jj];
      s = fmaf(a.x,r.x,fmaf(a.y,r.y,fmaf(a.z,r.z,fmaf(a.w,r.w,s))));
    }
    sT[b*64+c] = s;
    if (tid < 256){
      int which = tid>>6;
      float s2=0;
      #pragma unroll 8
      for (int jj=0;jj<32;jj++){
        float4 a = w2q[jj*66 + c];
        float4 r = srhsq[which*32+jj];
        s2 = fmaf(a.x,r.x,fmaf(a.y,r.y,fmaf(a.z,r.z,fmaf(a.w,r.w,s2))));
      }
      if (which<3) sE[which*64+c]=s2; else sg[c]=s2;
    }
  }
  __syncthreads();
  if (tid < 64){
    int c=tid;
    float e0=sE[c],e1=sE[64+c],e2=sE[128+c],gc=sg[c];
    float sumY = e0*smom[0]+e1*smom[1]+e2*smom[2];
    float sumYY = e0*e0*smom[3]+e1*e1*smom[6]+e2*e2*smom[8]
               + 2.f*(e0*e1*smom[4]+e0*e2*smom[5]+e1*e2*smom[7]);
    #pragma unroll
    for (int b=0;b<NB;b++){
      float nb = smom[9+b*4+3];
      float hb = gc + sT[b*64+c];
      float eS1b = e0*smom[9+b*4]+e1*smom[9+b*4+1]+e2*smom[9+b*4+2];
      sumY += nb*hb;
      sumYY += 2.f*hb*eS1b + nb*hb*hb;
    }
    float mean2 = sumY*invN;
    float var2 = sumYY*invN - mean2*mean2;
    float s2 = g2[c]*rsqrtf(var2+EPS);
    float t2 = b2[c]-mean2*s2;
    s_s2[c]=s2; s_t2[c]=t2;
    wsf[WS_E + c] = e0*s2; wsf[WS_E+64+c]=e1*s2; wsf[WS_E+128+c]=e2*s2;
  }
  __syncthreads();
  { int c=tid&63;
    if (tid < NB*64) wsf[WS_T + tid] = (sg[c]+sT[tid])*s_s2[c] + s_t2[c];
  }
}

// ---- kF: fused y2 -> bn2/relu -> z@W3.T + b3, LDS-transposed coalesced store ----
__global__ __launch_bounds__(256, 4) void kF(const float* __restrict__ feats,
                                             const int* __restrict__ bidx,
                                             const float* __restrict__ wsf,
                                             const float* __restrict__ b3,
                                             float* __restrict__ out) {
  __shared__ __align__(16) unsigned char SB[36992];
  unsigned* zbuf = (unsigned*)SB;            // 32768 B: 4 waves x 64 rows x 128B
  float* Tl = (float*)(SB + 32768);          // 16*66 = 4224 B
  float* fbuf = (float*)SB;                  // epilogue: [4][32][68] f32 = 34816 B
  int tid = threadIdx.x;
  for (int i=tid;i<NB*64;i+=256) Tl[(i>>6)*66 + (i&63)] = wsf[WS_T + i];
  int lane = tid & 63, wv = tid >> 6;
  int col = lane & 15, kgrp = lane >> 4;
  const ushort* w3b = (const ushort*)((const unsigned*)wsf + WS_W3);
  bf16x8 bfr[4][2];
  #pragma unroll
  for (int n=0;n<4;n++)
    #pragma unroll
    for (int kk=0;kk<2;kk++)
      bfr[n][kk] = *(const bf16x8*)(w3b + (n*16+col)*64 + kk*32 + kgrp*8);
  float bias[4];
  #pragma unroll
  for (int n=0;n<4;n++) bias[n] = b3[n*16+col];
  __syncthreads();
  const float* Eg = wsf + WS_E;
  int p0 = (blockIdx.x*4 + wv)*64;
  int p = p0 + lane;
  float f0 = feats[3*p], f1 = feats[3*p+1], f2 = feats[3*p+2];
  int b = bidx[p];
  const float* tb = &Tl[b*66];
  unsigned rowbase = (unsigned)(wv*64+lane)*32;
  unsigned sw = (lane&7)<<2;
  #pragma unroll
  for (int j=0;j<8;j++){
    unsigned w[4];
    #pragma unroll
    for (int q=0;q<4;q++){
      int c = j*8 + q*2;
      float2 tp = *(const float2*)(tb + c);
      float y0 = fmaf(Eg[c],  f0, fmaf(Eg[64+c],  f1, fmaf(Eg[128+c],  f2, tp.x)));
      float y1 = fmaf(Eg[c+1],f0, fmaf(Eg[64+c+1],f1, fmaf(Eg[128+c+1],f2, tp.y)));
      w[q] = pack2bf(fmaxf(y0,0.f), fmaxf(y1,0.f));
    }
    uint4 ch; ch.x=w[0]; ch.y=w[1]; ch.z=w[2]; ch.w=w[3];
    *(uint4*)&zbuf[rowbase + (((unsigned)(j*4)) ^ sw)] = ch;
  }
  __syncthreads();
  // load ALL A-fragments up front (zbuf gets overwritten by the epilogue)
  bf16x8 af[4][2];
  #pragma unroll
  for (int m=0;m<4;m++){
    int row = m*16 + col;
    unsigned rb = (unsigned)(wv*64+row)*32;
    unsigned sw2 = (unsigned)(row&7)<<2;
    #pragma unroll
    for (int kk=0;kk<2;kk++){
      unsigned off = ((unsigned)(kk*16 + kgrp*4)) ^ sw2;
      af[m][kk] = *(const bf16x8*)&zbuf[rb + off];
    }
  }
  __syncthreads();
  // two halves: rows [half*32, half*32+32) of each wave's 64-row tile
  #pragma unroll
  for (int half=0; half<2; half++){
    f32x4 acc[2][4];
    #pragma unroll
    for (int mi=0;mi<2;mi++)
      #pragma unroll
      for (int n=0;n<4;n++)
        acc[mi][n] = (f32x4){0.f,0.f,0.f,0.f};
    #pragma unroll
    for (int kk=0;kk<2;kk++)
      #pragma unroll
      for (int mi=0;mi<2;mi++)
        #pragma unroll
        for (int n=0;n<4;n++)
          acc[mi][n] = __builtin_amdgcn_mfma_f32_16x16x32_bf16(af[half*2+mi][kk], bfr[n][kk], acc[mi][n], 0,0,0);
    // scatter acc (+bias) into fbuf[wv][32][68]
    #pragma unroll
    for (int mi=0;mi<2;mi++){
      #pragma unroll
      for (int n=0;n<4;n++){
        #pragma unroll
        for (int r=0;r<4;r++)
          fbuf[wv*2176 + (mi*16 + kgrp*4 + r)*68 + n*16 + col] = acc[mi][n][r] + bias[n];
      }
    }
    __syncthreads();
    // coalesced readback + float4 store: 2048 float4s, 8 per thread
    #pragma unroll
    for (int it=0; it<8; it++){
      int idx = it*256 + tid;
      int gr = idx >> 4;                 // 0..127: (wave wv')*32 + local row
      int c4 = (idx & 15) * 4;
      float4 v = *(const float4*)&fbuf[(gr>>5)*2176 + (gr&31)*68 + c4];
      int orow = blockIdx.x*256 + (gr>>5)*64 + half*32 + (gr&31);
      *(float4*)&out[(size_t)orow*64 + c4] = v;
    }
    __syncthreads();
  }
}

extern "C" void kernel_launch(void* const* d_in, const int* in_sizes, int n_in,
                              void* d_out, int out_size, void* d_ws, size_t ws_size,
                              hipStream_t stream) {
  const float* feats = (const float*)d_in[0];
  const int*   bidx  = (const int*)d_in[1];
  const float* W1 = (const float*)d_in[2];
  const float* g1 = (const float*)d_in[3];
  const float* b1 = (const float*)d_in[4];
  const float* W2 = (const float*)d_in[5];
  const float* g2 = (const float*)d_in[6];
  const float* b2 = (const float*)d_in[7];
  const float* W3 = (const float*)d_in[8];
  const float* b3 = (const float*)d_in[9];
  float* wsf = (float*)d_ws;
  float* out = (float*)d_out;
  size_t need = (size_t)(WS_SMAX + (size_t)ACBLK*2048)*4;
  int mode = (ws_size >= need) ? 1 : 0;
  if (!mode) (void)hipMemsetAsync((char*)d_ws + (size_t)WS_MAXG*4, 0, 2048*4, stream);
  kAC<<<ACBLK, 256, 0, stream>>>(feats, bidx, W1, g1, wsf, mode);
  if (mode) kM<<<128, 256, 0, stream>>>(wsf);
  kB<<<1, 1024, 0, stream>>>(wsf, W1,g1,b1, W2,g2,b2, W3, mode);
  kF<<<1024, 256, 0, stream>>>(feats, bidx, wsf, b3, out);
}

// Round 10
// 60.303 us; speedup vs baseline: 6.6307x; 1.0030x over previous
//
#include <hip/hip_runtime.h>
#include <hip/hip_bf16.h>

#define EPS 1e-5f
#define NPTS 262144
#define NB 16
#define ACBLK 1024

typedef __attribute__((ext_vector_type(8))) short bf16x8;
typedef __attribute__((ext_vector_type(4))) float f32x4;

// ws float/u32 offsets
#define WS_E    0        // 192 f
#define WS_T    192      // 1024 f
#define WS_W3   1216     // 2048 u32
#define WS_MAXG 3264     // 2048 u32 fallback merged maxima (memset 0 in mode 0)
#define WS_PMOM 5312     // 16*73 f kM partial moments
#define WS_SCRM 6480     // 1024*73 f per-block moments(9)+hist(64)
#define WS_PART 81232    // 16*2048 u32 kM partial maxima
#define WS_SMAX 114000   // 1024*2048 u32 per-block maxima

__device__ inline float decodeu(unsigned u){
  unsigned bits = (u & 0x80000000u) ? (u ^ 0x80000000u) : ~u;
  return __uint_as_float(bits);
}
__device__ inline unsigned f2bf(float f){
  unsigned u = __float_as_uint(f);
  return (u + 0x7FFFu + ((u>>16)&1u)) >> 16;
}
__device__ inline unsigned pack2bf(float lo, float hi){
  return (f2bf(hi)<<16) | (f2bf(lo) & 0xFFFFu);
}
__device__ inline unsigned ordu(float v){
  unsigned bits = __float_as_uint(v);
  return bits ^ (unsigned)(((int)bits>>31) | (int)0x80000000);
}

// ---- kAC: fused moments + per-batch directional max of feats@W1'^T ----
// 1024 blocks x 256 thr; block owns 256 points (1/thread, LDS-staged).
// Each wave owns a DISJOINT 64-point set and ALL 128 channels (2/lane):
// one broadcast ds_read_b128 per point per block (256 total, was 512).
__global__ __launch_bounds__(256) void kAC(const float* __restrict__ feats,
                                           const int* __restrict__ bidx,
                                           const float* __restrict__ W1,
                                           const float* __restrict__ g1,
                                           float* __restrict__ wsf, int mode) {
  __shared__ unsigned lmax[NB*128];
  __shared__ __align__(16) float4 sfeat[256];
  __shared__ float hist[NB*4];
  __shared__ float red[4*9];
  int tid = threadIdx.x;
  for (int i=tid;i<NB*128;i+=256) lmax[i]=0u;
  if (tid < NB*4) hist[tid]=0.f;
  __syncthreads();
  int p = blockIdx.x*256 + tid;
  float f0=feats[3*p], f1=feats[3*p+1], f2=feats[3*p+2];
  int b = bidx[p];
  sfeat[tid] = make_float4(f0,f1,f2,__int_as_float(b));
  atomicAdd(&hist[b*4+0],f0);
  atomicAdd(&hist[b*4+1],f1);
  atomicAdd(&hist[b*4+2],f2);
  atomicAdd(&hist[b*4+3],1.0f);
  int lane = tid&63, wv = tid>>6;
  { float acc[9]={f0,f1,f2,f0*f0,f0*f1,f0*f2,f1*f1,f1*f2,f2*f2};
    #pragma unroll
    for (int k=0;k<9;k++){
      float v=acc[k];
      v+=__shfl_down(v,32); v+=__shfl_down(v,16); v+=__shfl_down(v,8);
      v+=__shfl_down(v,4);  v+=__shfl_down(v,2);  v+=__shfl_down(v,1);
      if (lane==0) red[wv*9+k]=v;
    }
  }
  __syncthreads();
  // channels: c0 = lane, c1 = lane+64
  int c0 = lane, c1 = lane+64;
  float sg0 = (g1[c0]>=0.f)?1.f:-1.f;
  float sg1 = (g1[c1]>=0.f)?1.f:-1.f;
  float w00=W1[3*c0]*sg0, w01=W1[3*c0+1]*sg0, w02=W1[3*c0+2]*sg0;
  float w10=W1[3*c1]*sg1, w11=W1[3*c1+1]*sg1, w12=W1[3*c1+2]*sg1;
  const float4* sp = &sfeat[wv*64];
  float m0[16], m1[16];
  #pragma unroll
  for (int q=0;q<16;q++){ m0[q] = -__builtin_inff(); m1[q] = -__builtin_inff(); }
  #pragma unroll 8
  for (int k=0;k<64;k++){
    float4 f = sp[k];                       // broadcast ds_read_b128
    float v0 = fmaf(f.z,w02,fmaf(f.y,w01,f.x*w00));
    float v1 = fmaf(f.z,w12,fmaf(f.y,w11,f.x*w10));
    int sbb = __builtin_amdgcn_readfirstlane(__float_as_int(f.w));
    switch (sbb){
      case 0:  m0[0]=fmaxf(m0[0],v0);  m1[0]=fmaxf(m1[0],v1);  break;
      case 1:  m0[1]=fmaxf(m0[1],v0);  m1[1]=fmaxf(m1[1],v1);  break;
      case 2:  m0[2]=fmaxf(m0[2],v0);  m1[2]=fmaxf(m1[2],v1);  break;
      case 3:  m0[3]=fmaxf(m0[3],v0);  m1[3]=fmaxf(m1[3],v1);  break;
      case 4:  m0[4]=fmaxf(m0[4],v0);  m1[4]=fmaxf(m1[4],v1);  break;
      case 5:  m0[5]=fmaxf(m0[5],v0);  m1[5]=fmaxf(m1[5],v1);  break;
      case 6:  m0[6]=fmaxf(m0[6],v0);  m1[6]=fmaxf(m1[6],v1);  break;
      case 7:  m0[7]=fmaxf(m0[7],v0);  m1[7]=fmaxf(m1[7],v1);  break;
      case 8:  m0[8]=fmaxf(m0[8],v0);  m1[8]=fmaxf(m1[8],v1);  break;
      case 9:  m0[9]=fmaxf(m0[9],v0);  m1[9]=fmaxf(m1[9],v1);  break;
      case 10: m0[10]=fmaxf(m0[10],v0); m1[10]=fmaxf(m1[10],v1); break;
      case 11: m0[11]=fmaxf(m0[11],v0); m1[11]=fmaxf(m1[11],v1); break;
      case 12: m0[12]=fmaxf(m0[12],v0); m1[12]=fmaxf(m1[12],v1); break;
      case 13: m0[13]=fmaxf(m0[13],v0); m1[13]=fmaxf(m1[13],v1); break;
      case 14: m0[14]=fmaxf(m0[14],v0); m1[14]=fmaxf(m1[14],v1); break;
      default: m0[15]=fmaxf(m0[15],v0); m1[15]=fmaxf(m1[15],v1); break;
    }
  }
  #pragma unroll
  for (int q=0;q<16;q++){
    if (m0[q] > -__builtin_inff()) atomicMax(&lmax[q*128+c0], ordu(m0[q]));
    if (m1[q] > -__builtin_inff()) atomicMax(&lmax[q*128+c1], ordu(m1[q]));
  }
  __syncthreads();
  float* scrM = wsf + WS_SCRM + blockIdx.x*73;
  if (tid<9) scrM[tid]=red[tid]+red[9+tid]+red[18+tid]+red[27+tid];
  if (tid>=64 && tid<128) scrM[9+tid-64]=hist[tid-64];
  if (mode){
    unsigned* spo = (unsigned*)wsf + WS_SMAX + (size_t)blockIdx.x*2048;
    for (int i=tid;i<2048;i+=256) spo[i]=lmax[i];
  } else {
    unsigned* mg = (unsigned*)wsf + WS_MAXG;
    for (int i=tid;i<2048;i+=256){ unsigned v=lmax[i]; if(v) atomicMax(&mg[i],v); }
  }
}

// ---- kM: tree-merge per-block maxima 1024->16, moments 1024->16 ----
__global__ __launch_bounds__(256) void kM(float* __restrict__ wsf){
  int g = blockIdx.x >> 3, ec = blockIdx.x & 7;
  int e = ec*256 + threadIdx.x;
  const unsigned* smax = (const unsigned*)wsf + WS_SMAX;
  unsigned m = 0;
  #pragma unroll 4
  for (int k=g*64;k<g*64+64;k++){ unsigned t=smax[(size_t)k*2048+e]; m = t>m?t:m; }
  ((unsigned*)wsf)[WS_PART + g*2048 + e] = m;
  if (ec==0 && threadIdx.x<73){
    float s=0; const float* sm0 = wsf + WS_SCRM;
    #pragma unroll 4
    for (int k=g*64;k<g*64+64;k++) s += sm0[k*73+threadIdx.x];
    wsf[WS_PMOM + g*73 + threadIdx.x] = s;
  }
}

// ---- kB: all tiny math (single block, 1024 thr, float4 LDS dots) ----
__global__ __launch_bounds__(1024) void kB(float* __restrict__ wsf,
    const float* __restrict__ W1, const float* __restrict__ g1, const float* __restrict__ b1,
    const float* __restrict__ W2, const float* __restrict__ g2, const float* __restrict__ b2,
    const float* __restrict__ W3, int mode) {
  __shared__ __align__(16) float4 w2q[64*66];
  __shared__ __align__(16) float4 smbnq[NB*32];
  __shared__ __align__(16) float4 srhsq[4*32];
  __shared__ float s_w1[384];
  __shared__ float s_sc[128], s_sh[128], sE[3*64], sg[64], sT[NB*64];
  __shared__ float smom[80], s_s2[64], s_t2[64];
  int tid = threadIdx.x;
  float4 rw[4];
  #pragma unroll
  for (int t=0;t<4;t++) rw[t] = ((const float4*)W2)[tid + t*1024];
  float4 rw3 = ((const float4*)W3)[tid];
  if (tid<384) s_w1[tid]=W1[tid];
  #pragma unroll
  for (int t=0;t<4;t++){
    int q = tid + t*1024;
    w2q[(q&63)*66 + (q>>6)] = rw[t];
  }
  { unsigned* w3u = (unsigned*)wsf + WS_W3;
    w3u[2*tid]   = pack2bf(rw3.x, rw3.y);
    w3u[2*tid+1] = pack2bf(rw3.z, rw3.w);
  }
  if (mode){
    if (tid<73){ float s=0;
      #pragma unroll
      for (int g=0;g<16;g++) s += wsf[WS_PMOM+g*73+tid];
      smom[tid]=s; }
  } else {
    if (tid<73){ float s=0; const float* sm0=wsf+WS_SCRM;
      for (int k=0;k<ACBLK;k++) s += sm0[k*73+tid];
      smom[tid]=s; }
  }
  __syncthreads();
  const float invN = 1.0f/NPTS;
  if (tid < 128){
    int c=tid; float w0=s_w1[3*c],w1=s_w1[3*c+1],w2=s_w1[3*c+2];
    float mean = (w0*smom[0]+w1*smom[1]+w2*smom[2])*invN;
    float ex2 = (w0*w0*smom[3]+w1*w1*smom[6]+w2*w2*smom[8]
               + 2.f*(w0*w1*smom[4]+w0*w2*smom[5]+w1*w2*smom[7]))*invN;
    float var = ex2 - mean*mean;
    float sc = g1[c]*rsqrtf(var+EPS);
    s_sc[c]=sc; s_sh[c]=b1[c]-mean*sc;
  }
  __syncthreads();
  { const unsigned* part=(const unsigned*)wsf+WS_PART;
    const unsigned* mg=(const unsigned*)wsf+WS_MAXG;
    float* smbnf = (float*)smbnq;
    #pragma unroll
    for (int i=tid;i<NB*128;i+=1024){
      unsigned u;
      if (mode){ u=0;
        #pragma unroll
        for (int g=0;g<16;g++){ unsigned t=part[g*2048+i]; u = t>u?t:u; }
      } else u = mg[i];
      float M = decodeu(u);
      int ch=i&127;
      smbnf[i] = fabsf(s_sc[ch])*M + s_sh[ch];
    } }
  if (tid < 512){
    int which = tid>>7, j = tid&127;
    ((float*)srhsq)[tid] = (which<3) ? s_sc[j]*s_w1[3*j+which] : s_sh[j];
  }
  __syncthreads();
  { int c = tid&63, b = tid>>6;
    const float4* rq = &smbnq[b*32];
    float s=0;
    #pragma unroll 8
    for (int jj=0;jj<32;jj++){
      float4 a = w2q[(32+jj)*66 + c];
      float4 r = rq[jj];
      s = fmaf(a.x,r.x,fmaf(a.y,r.y,fmaf(a.z,r.z,fmaf(a.w,r.w,s))));
    }
    sT[b*64+c] = s;
    if (tid < 256){
      int which = tid>>6;
      float s2=0;
      #pragma unroll 8
      for (int jj=0;jj<32;jj++){
        float4 a = w2q[jj*66 + c];
        float4 r = srhsq[which*32+jj];
        s2 = fmaf(a.x,r.x,fmaf(a.y,r.y,fmaf(a.z,r.z,fmaf(a.w,r.w,s2))));
      }
      if (which<3) sE[which*64+c]=s2; else sg[c]=s2;
    }
  }
  __syncthreads();
  if (tid < 64){
    int c=tid;
    float e0=sE[c],e1=sE[64+c],e2=sE[128+c],gc=sg[c];
    float sumY = e0*smom[0]+e1*smom[1]+e2*smom[2];
    float sumYY = e0*e0*smom[3]+e1*e1*smom[6]+e2*e2*smom[8]
               + 2.f*(e0*e1*smom[4]+e0*e2*smom[5]+e1*e2*smom[7]);
    #pragma unroll
    for (int b=0;b<NB;b++){
      float nb = smom[9+b*4+3];
      float hb = gc + sT[b*64+c];
      float eS1b = e0*smom[9+b*4]+e1*smom[9+b*4+1]+e2*smom[9+b*4+2];
      sumY += nb*hb;
      sumYY += 2.f*hb*eS1b + nb*hb*hb;
    }
    float mean2 = sumY*invN;
    float var2 = sumYY*invN - mean2*mean2;
    float s2 = g2[c]*rsqrtf(var2+EPS);
    float t2 = b2[c]-mean2*s2;
    s_s2[c]=s2; s_t2[c]=t2;
    wsf[WS_E + c] = e0*s2; wsf[WS_E+64+c]=e1*s2; wsf[WS_E+128+c]=e2*s2;
  }
  __syncthreads();
  { int c=tid&63;
    if (tid < NB*64) wsf[WS_T + tid] = (sg[c]+sT[tid])*s_s2[c] + s_t2[c];
  }
}

// ---- kF: fused y2 -> bn2/relu -> z@W3.T + b3, LDS-transposed coalesced store ----
__global__ __launch_bounds__(256, 4) void kF(const float* __restrict__ feats,
                                             const int* __restrict__ bidx,
                                             const float* __restrict__ wsf,
                                             const float* __restrict__ b3,
                                             float* __restrict__ out) {
  __shared__ __align__(16) unsigned char SB[36992];
  unsigned* zbuf = (unsigned*)SB;            // 32768 B: 4 waves x 64 rows x 128B
  float* Tl = (float*)(SB + 32768);          // 16*66 = 4224 B
  float* fbuf = (float*)SB;                  // epilogue: [4][32][68] f32
  int tid = threadIdx.x;
  for (int i=tid;i<NB*64;i+=256) Tl[(i>>6)*66 + (i&63)] = wsf[WS_T + i];
  int lane = tid & 63, wv = tid >> 6;
  int col = lane & 15, kgrp = lane >> 4;
  const ushort* w3b = (const ushort*)((const unsigned*)wsf + WS_W3);
  bf16x8 bfr[4][2];
  #pragma unroll
  for (int n=0;n<4;n++)
    #pragma unroll
    for (int kk=0;kk<2;kk++)
      bfr[n][kk] = *(const bf16x8*)(w3b + (n*16+col)*64 + kk*32 + kgrp*8);
  float bias[4];
  #pragma unroll
  for (int n=0;n<4;n++) bias[n] = b3[n*16+col];
  __syncthreads();
  const float* Eg = wsf + WS_E;
  int p0 = (blockIdx.x*4 + wv)*64;
  int p = p0 + lane;
  float f0 = feats[3*p], f1 = feats[3*p+1], f2 = feats[3*p+2];
  int b = bidx[p];
  const float* tb = &Tl[b*66];
  unsigned rowbase = (unsigned)(wv*64+lane)*32;
  unsigned sw = (lane&7)<<2;
  #pragma unroll
  for (int j=0;j<8;j++){
    unsigned w[4];
    #pragma unroll
    for (int q=0;q<4;q++){
      int c = j*8 + q*2;
      float2 tp = *(const float2*)(tb + c);
      float y0 = fmaf(Eg[c],  f0, fmaf(Eg[64+c],  f1, fmaf(Eg[128+c],  f2, tp.x)));
      float y1 = fmaf(Eg[c+1],f0, fmaf(Eg[64+c+1],f1, fmaf(Eg[128+c+1],f2, tp.y)));
      w[q] = pack2bf(fmaxf(y0,0.f), fmaxf(y1,0.f));
    }
    uint4 ch; ch.x=w[0]; ch.y=w[1]; ch.z=w[2]; ch.w=w[3];
    *(uint4*)&zbuf[rowbase + (((unsigned)(j*4)) ^ sw)] = ch;
  }
  __syncthreads();
  bf16x8 af[4][2];
  #pragma unroll
  for (int m=0;m<4;m++){
    int row = m*16 + col;
    unsigned rb = (unsigned)(wv*64+row)*32;
    unsigned sw2 = (unsigned)(row&7)<<2;
    #pragma unroll
    for (int kk=0;kk<2;kk++){
      unsigned off = ((unsigned)(kk*16 + kgrp*4)) ^ sw2;
      af[m][kk] = *(const bf16x8*)&zbuf[rb + off];
    }
  }
  __syncthreads();
  #pragma unroll
  for (int half=0; half<2; half++){
    f32x4 acc[2][4];
    #pragma unroll
    for (int mi=0;mi<2;mi++)
      #pragma unroll
      for (int n=0;n<4;n++)
        acc[mi][n] = (f32x4){0.f,0.f,0.f,0.f};
    #pragma unroll
    for (int kk=0;kk<2;kk++)
      #pragma unroll
      for (int mi=0;mi<2;mi++)
        #pragma unroll
        for (int n=0;n<4;n++)
          acc[mi][n] = __builtin_amdgcn_mfma_f32_16x16x32_bf16(af[half*2+mi][kk], bfr[n][kk], acc[mi][n], 0,0,0);
    #pragma unroll
    for (int mi=0;mi<2;mi++){
      #pragma unroll
      for (int n=0;n<4;n++){
        #pragma unroll
        for (int r=0;r<4;r++)
          fbuf[wv*2176 + (mi*16 + kgrp*4 + r)*68 + n*16 + col] = acc[mi][n][r] + bias[n];
      }
    }
    __syncthreads();
    #pragma unroll
    for (int it=0; it<8; it++){
      int idx = it*256 + tid;
      int gr = idx >> 4;
      int c4 = (idx & 15) * 4;
      float4 v = *(const float4*)&fbuf[(gr>>5)*2176 + (gr&31)*68 + c4];
      int orow = blockIdx.x*256 + (gr>>5)*64 + half*32 + (gr&31);
      *(float4*)&out[(size_t)orow*64 + c4] = v;
    }
    __syncthreads();
  }
}

extern "C" void kernel_launch(void* const* d_in, const int* in_sizes, int n_in,
                              void* d_out, int out_size, void* d_ws, size_t ws_size,
                              hipStream_t stream) {
  const float* feats = (const float*)d_in[0];
  const int*   bidx  = (const int*)d_in[1];
  const float* W1 = (const float*)d_in[2];
  const float* g1 = (const float*)d_in[3];
  const float* b1 = (const float*)d_in[4];
  const float* W2 = (const float*)d_in[5];
  const float* g2 = (const float*)d_in[6];
  const float* b2 = (const float*)d_in[7];
  const float* W3 = (const float*)d_in[8];
  const float* b3 = (const float*)d_in[9];
  float* wsf = (float*)d_ws;
  float* out = (float*)d_out;
  size_t need = (size_t)(WS_SMAX + (size_t)ACBLK*2048)*4;
  int mode = (ws_size >= need) ? 1 : 0;
  if (!mode) (void)hipMemsetAsync((char*)d_ws + (size_t)WS_MAXG*4, 0, 2048*4, stream);
  kAC<<<ACBLK, 256, 0, stream>>>(feats, bidx, W1, g1, wsf, mode);
  if (mode) kM<<<128, 256, 0, stream>>>(wsf);
  kB<<<1, 1024, 0, stream>>>(wsf, W1,g1,b1, W2,g2,b2, W3, mode);
  kF<<<1024, 256, 0, stream>>>(feats, bidx, wsf, b3, out);
}